// Round 5
// baseline (20171.536 us; speedup 1.0000x reference)
//
#include <hip/hip_runtime.h>
#include <math.h>

// ---------------------------------------------------------------------------
// Persistent-RNN LSTM for MI355X.
//   B=128, T=512, IN=64, H=1024, 2 layers, head OUT=1 on last step.
// Design:
//  - 256 WGs x 512 threads (8 waves), cooperative launch, 1 WG/CU.
//  - Weights f16-resident: layer0 [Uh0|Wx0] slice (16 rows x 1088) in LDS
//    (35 KB); layer1 [Wx1/Uh1] slice in VGPRs (32 half8 frags/lane = 128 VGPR).
//  - WG owns 4 h-columns => 16 gate rows (order i0..3,f0..3,o0..3,g0..3).
//  - mfma_f32_16x16x32_f16: A = h-state frags from global (f16), B = weights.
//  - Software pipeline: iter s computes layer1(s) AND layer0(s+1), sharing
//    h0(s) fragment loads. 513 grid barriers total.
//  - Layer1 K=2048 split: waves 0-3 k<1024 (A=h0), waves 4-7 k>=1024 (A=h1);
//    partials exchanged via LDS. Waves 0-3 also compute BOTH layer0 tiles
//    (fused with their h0 loads); acc for tile 2p+1 handed to wave 4+p.
//  - BLOCKED h layout h[parity][kblk=256][batch=128][4] f16:
//      * writer: WG wg owns kblk=wg -> 1 KB contiguous block per step =
//        16 FULL 64B lines -> write-through stores cover whole lines, no
//        memory-side write-allocate RMW (round-4 counters: 2.2 MB/step HBM
//        FETCH + 4x WRITE amplification from 8B slivers in row-major).
//      * reader: h[b][k] = buf[(k>>2)*128 + b][k&3]; a half8 A-fragment is
//        two 8B loads (kblk, kblk+1) recombined; 16-lane groups remain
//        128B-contiguous (coalesced).
//  - Cell math fp32 with fast __expf/__fdividef sigmoid/tanh (saturating,
//    no NaN path); c-state in registers; gate gather via shfl_xor(4,8,12).
//  - Fence-light grid barrier: BYTE-IDENTICAL to the round-4 kernel that
//    passed (WT h-stores sc0 sc1; static arrival tree garr[wg>>5], group
//    leaders aggregate 32 into global; XCD leaders poll global, buffer_inv
//    sc1 AFTER the poll, release per-XCD flag; followers poll flag then L1
//    buffer_inv).
// ---------------------------------------------------------------------------

#define Hd 1024
#define Bd 128
#define Td 512
#define INd 64
#define NWG 256
#define NTHR 512

typedef _Float16 f16;
typedef _Float16 half8 __attribute__((ext_vector_type(8)));
typedef _Float16 half4 __attribute__((ext_vector_type(4)));
typedef float f32x4 __attribute__((ext_vector_type(4)));

// sync[] layout (uint index):
//   [0]           : global step counter (group leaders add 32; target 256*ep)
//   [32 + 32*g]   : per-group arrival counter (monotonic), g = wg>>5
//   [288 + 32*x]  : per-XCD release flag (epoch), x = physical XCD
//   [608 + x]     : per-XCD leader-election counter
// zero first 640 uints.

__device__ __forceinline__ float fsigm(float x) {
    // 1/(1+e^-x); exp overflow -> inf -> rcp -> 0 (correct saturation)
    return __fdividef(1.f, 1.f + __expf(-x));
}
__device__ __forceinline__ float ftanh_(float x) {
    // tanh(x) = 1 - 2/(e^(2x)+1); both +-inf limits correct
    return 1.f - __fdividef(2.f, 1.f + __expf(2.f * x));
}

// ---------------- init: bi0/bi1, zero h buffers, zero sync ----------------
__global__ __launch_bounds__(512) void init_state(
    const float* __restrict__ bnd, const float* __restrict__ Wb0,
    const float* __restrict__ bb0, const float* __restrict__ Wb1,
    const float* __restrict__ bb1,
    float* __restrict__ bi0, float* __restrict__ bi1,
    f16* __restrict__ h0buf, f16* __restrict__ h1buf,
    unsigned int* __restrict__ sync)
{
    int idx = blockIdx.x * 512 + threadIdx.x;   // [0, B*H)
    int b = idx >> 10;
    int h = idx & 1023;
    float b0v = bnd[b * 2 + 0], b1v = bnd[b * 2 + 1];
    bi0[idx] = b0v * Wb0[h * 2 + 0] + b1v * Wb0[h * 2 + 1] + bb0[h];
    bi1[idx] = b0v * Wb1[h * 2 + 0] + b1v * Wb1[h * 2 + 1] + bb1[h];
    h0buf[idx] = (f16)0.f;  h0buf[idx + Bd * Hd] = (f16)0.f;
    h1buf[idx] = (f16)0.f;  h1buf[idx + Bd * Hd] = (f16)0.f;
    if (idx < 640) sync[idx] = 0u;
}

// ---------------- transpose x [B,T,IN] f32 -> xT [T,B,IN] f16 ----------------
__global__ __launch_bounds__(512) void xpose(
    const float* __restrict__ x, f16* __restrict__ xT)
{
    int idx = blockIdx.x * 512 + threadIdx.x;   // [0, B*T*IN)
    int b = idx >> 15;           // T*IN = 32768
    int t = (idx >> 6) & 511;
    int i = idx & 63;
    xT[((size_t)t * Bd + b) * INd + i] = (f16)x[idx];
}

// ---------------- persistent LSTM ----------------
__global__ __launch_bounds__(NTHR, 2) void lstm_persist(
    const f16* __restrict__ xT,
    f16* __restrict__ h0buf, f16* __restrict__ h1buf,
    const float* __restrict__ bi0, const float* __restrict__ bi1,
    const float* __restrict__ Wx0, const float* __restrict__ bx0,
    const float* __restrict__ Uh0, const float* __restrict__ bh0,
    const float* __restrict__ Wx1, const float* __restrict__ bx1,
    const float* __restrict__ Uh1, const float* __restrict__ bh1,
    const float* __restrict__ fcW, const float* __restrict__ fcb,
    float* __restrict__ out, unsigned int* __restrict__ sync)
{
    const int tid  = threadIdx.x;
    const int w    = tid >> 6;        // wave 0..7
    const int lane = tid & 63;
    const int n    = lane & 15;       // frag col (gate-col within WG)
    const int q    = lane >> 4;       // 0..3
    const int wg   = blockIdx.x;
    const int c0wg = wg * 4;          // h-column base of this WG
    const int hcol = c0wg + (n & 3);
    const int gid  = n >> 2;          // gate group of my frag col
    const bool lowhalf = (w < 4);
    const int p    = lowhalf ? w : (w - 4);
    const int mt   = lowhalf ? 2 * p : 2 * p + 1;  // my cell tile (both layers)
    const size_t S = (size_t)Bd * Hd;

    __shared__ f16 B0[16 * 1096];       // layer0 weights [16 rows][1088+8 pad]
    __shared__ float xchg[3072];        // 12 exchange slots x 256 floats

    // ---- static arrival group + physical-XCD leader election ----
    const bool glead = ((wg & 31) == 0);           // logical group leader
    unsigned int* garr = sync + 32 + 32 * (wg >> 5);
    int  xcd  = 0;
    bool lead = false;                              // physical-XCD inv leader
    unsigned int* relp = nullptr;
    if (tid == 0) {
        asm volatile("s_getreg_b32 %0, hwreg(HW_REG_XCC_ID)" : "=s"(xcd));
        xcd &= 7;
        unsigned r = __hip_atomic_fetch_add(&sync[608 + xcd], 1u,
                         __ATOMIC_RELAXED, __HIP_MEMORY_SCOPE_AGENT);
        lead = (r == 0u);
        relp = sync + 288 + 32 * xcd;
    }

    // ---- fill B0 (f32 -> f16): row nr -> global gate row ----
    {
        int nr = tid >> 5;              // 0..15
        int gr = (nr >> 2) * Hd + c0wg + (nr & 3);
        for (int k = tid & 31; k < 1088; k += 32) {
            float v = (k < Hd) ? Uh0[(size_t)gr * Hd + k]
                               : Wx0[(size_t)gr * INd + (k - Hd)];
            B0[nr * 1096 + k] = (f16)v;
        }
    }

    // ---- preload layer1 B frags into VGPRs (my k-half) ----
    half8 b1f[32];
    {
        const float* Wsrc = lowhalf ? Wx1 : Uh1;
        int gr = gid * Hd + c0wg + (n & 3);
        const float* rp = Wsrc + (size_t)gr * Hd + q * 8;
        #pragma unroll
        for (int kk = 0; kk < 32; ++kk) {
            half8 hv;
            #pragma unroll
            for (int j = 0; j < 8; ++j) hv[j] = (f16)rp[kk * 32 + j];
            b1f[kk] = hv;
        }
    }

    // ---- per-lane biases & c-state ----
    float gb0[4], gb1[4], bia0[4], bia1[4];
    #pragma unroll
    for (int g = 0; g < 4; ++g) {
        gb0[g] = bx0[g * Hd + hcol] + bh0[g * Hd + hcol];
        gb1[g] = bx1[g * Hd + hcol] + bh1[g * Hd + hcol];
    }
    #pragma unroll
    for (int r = 0; r < 4; ++r) {
        int row = mt * 16 + q * 4 + r;
        bia0[r] = bi0[row * Hd + hcol];
        bia1[r] = bi1[row * Hd + hcol];
    }
    f32x4 c0v = {0.f, 0.f, 0.f, 0.f};
    f32x4 c1v = {0.f, 0.f, 0.f, 0.f};

    __syncthreads();   // B0 ready

    unsigned epoch = 0;

    // batch rows of my two A tiles (lowhalf: h0 tiles; highhalf: h1 tiles)
    const int ra = 2 * p * 16 + n;
    const int rb = (2 * p + 1) * 16 + n;

    for (int s = -1; s <= 511; ++s) {
        const bool do_l0 = (s < 511);
        const bool do_l1 = (s >= 0);
        const int pr = s & 1;                 // s=-1 -> 1
        const f16* h0r = h0buf + (size_t)pr * S;
        f16*       h0w = h0buf + (size_t)(1 - pr) * S;
        const f16* h1r = h1buf + (size_t)(1 - pr) * S;
        f16*       h1w = h1buf + (size_t)pr * S;

        f32x4 a0a = {0.f,0.f,0.f,0.f}, a0b = {0.f,0.f,0.f,0.f};
        f32x4 a1a = {0.f,0.f,0.f,0.f}, a1b = {0.f,0.f,0.f,0.f};

        if (lowhalf) {
            const half4* hb = (const half4*)h0r;   // blocked: [(kblk)*128+b][4]
            const half8* pB  = (const half8*)(&B0[n * 1096 + q * 8]);
            if (do_l0 && do_l1) {
                #pragma unroll
                for (int kk = 0; kk < 32; ++kk) {
                    int kb = q * 2 + kk * 8;
                    half4 a0lo = hb[(kb    ) * 128 + ra];
                    half4 a0hi = hb[(kb + 1) * 128 + ra];
                    half4 a1lo = hb[(kb    ) * 128 + rb];
                    half4 a1hi = hb[(kb + 1) * 128 + rb];
                    half8 A0 = __builtin_shufflevector(a0lo, a0hi, 0,1,2,3,4,5,6,7);
                    half8 A1 = __builtin_shufflevector(a1lo, a1hi, 0,1,2,3,4,5,6,7);
                    half8 Bl = pB[kk*4];
                    a0a = __builtin_amdgcn_mfma_f32_16x16x32_f16(A0, Bl, a0a, 0,0,0);
                    a0b = __builtin_amdgcn_mfma_f32_16x16x32_f16(A1, Bl, a0b, 0,0,0);
                    a1a = __builtin_amdgcn_mfma_f32_16x16x32_f16(A0, b1f[kk], a1a, 0,0,0);
                    a1b = __builtin_amdgcn_mfma_f32_16x16x32_f16(A1, b1f[kk], a1b, 0,0,0);
                }
            } else if (do_l0) {          // s == -1
                #pragma unroll
                for (int kk = 0; kk < 32; ++kk) {
                    int kb = q * 2 + kk * 8;
                    half4 a0lo = hb[(kb    ) * 128 + ra];
                    half4 a0hi = hb[(kb + 1) * 128 + ra];
                    half4 a1lo = hb[(kb    ) * 128 + rb];
                    half4 a1hi = hb[(kb + 1) * 128 + rb];
                    half8 A0 = __builtin_shufflevector(a0lo, a0hi, 0,1,2,3,4,5,6,7);
                    half8 A1 = __builtin_shufflevector(a1lo, a1hi, 0,1,2,3,4,5,6,7);
                    half8 Bl = pB[kk*4];
                    a0a = __builtin_amdgcn_mfma_f32_16x16x32_f16(A0, Bl, a0a, 0,0,0);
                    a0b = __builtin_amdgcn_mfma_f32_16x16x32_f16(A1, Bl, a0b, 0,0,0);
                }
            } else {                     // s == 511
                #pragma unroll
                for (int kk = 0; kk < 32; ++kk) {
                    int kb = q * 2 + kk * 8;
                    half4 a0lo = hb[(kb    ) * 128 + ra];
                    half4 a0hi = hb[(kb + 1) * 128 + ra];
                    half4 a1lo = hb[(kb    ) * 128 + rb];
                    half4 a1hi = hb[(kb + 1) * 128 + rb];
                    half8 A0 = __builtin_shufflevector(a0lo, a0hi, 0,1,2,3,4,5,6,7);
                    half8 A1 = __builtin_shufflevector(a1lo, a1hi, 0,1,2,3,4,5,6,7);
                    a1a = __builtin_amdgcn_mfma_f32_16x16x32_f16(A0, b1f[kk], a1a, 0,0,0);
                    a1b = __builtin_amdgcn_mfma_f32_16x16x32_f16(A1, b1f[kk], a1b, 0,0,0);
                }
            }
            if (do_l0) {                 // x-projection chunks (k = 1024..1087)
                const f16* xt = xT + (size_t)(s + 1) * Bd * INd;
                const half8* pX0 = (const half8*)(xt + (size_t)(2*p*16 + n) * INd + q*8);
                const half8* pX1 = (const half8*)(xt + (size_t)((2*p+1)*16 + n) * INd + q*8);
                #pragma unroll
                for (int kk = 0; kk < 2; ++kk) {
                    half8 Bl = pB[(32 + kk) * 4];
                    a0a = __builtin_amdgcn_mfma_f32_16x16x32_f16(pX0[kk*4], Bl, a0a, 0,0,0);
                    a0b = __builtin_amdgcn_mfma_f32_16x16x32_f16(pX1[kk*4], Bl, a0b, 0,0,0);
                }
            }
        } else if (do_l1) {              // waves 4-7: layer1 k-half 1 (A = h1)
            const half4* hb = (const half4*)h1r;
            #pragma unroll
            for (int kk = 0; kk < 32; ++kk) {
                int kb = q * 2 + kk * 8;
                half4 a0lo = hb[(kb    ) * 128 + ra];
                half4 a0hi = hb[(kb + 1) * 128 + ra];
                half4 a1lo = hb[(kb    ) * 128 + rb];
                half4 a1hi = hb[(kb + 1) * 128 + rb];
                half8 A0 = __builtin_shufflevector(a0lo, a0hi, 0,1,2,3,4,5,6,7);
                half8 A1 = __builtin_shufflevector(a1lo, a1hi, 0,1,2,3,4,5,6,7);
                a1a = __builtin_amdgcn_mfma_f32_16x16x32_f16(A0, b1f[kk], a1a, 0,0,0);
                a1b = __builtin_amdgcn_mfma_f32_16x16x32_f16(A1, b1f[kk], a1b, 0,0,0);
            }
        }

        // ---- exchange partials via LDS ----
        float* slotA = xchg;              // layer0 tile 2p+1 (from wave p)
        float* slotB = xchg + 1024;       // layer1 tile 2p+1 k-half0 (from wave p)
        float* slotC = xchg + 2048;       // layer1 tile 2p   k-half1 (from wave 4+p)
        if (lowhalf) {
            if (do_l0) *(f32x4*)&slotA[p * 256 + lane * 4] = a0b;
            if (do_l1) *(f32x4*)&slotB[p * 256 + lane * 4] = a1b;
        } else {
            if (do_l1) *(f32x4*)&slotC[p * 256 + lane * 4] = a1a;
        }
        __syncthreads();

        f32x4 g0acc, g1acc;
        if (lowhalf) {
            g0acc = a0a;
            if (do_l1) g1acc = a1a + *(const f32x4*)&slotC[p * 256 + lane * 4];
        } else {
            if (do_l0) g0acc = *(const f32x4*)&slotA[p * 256 + lane * 4];
            if (do_l1) g1acc = a1b + *(const f32x4*)&slotB[p * 256 + lane * 4];
        }

        // ---- cell updates (fp32), write h (f16, device-coherent WT) ----
        // blocked store: f16 index ((wg*128 + row)*4 + n), n<4 -> the WG
        // writes a contiguous 1 KB block (16 full 64B lines) per buffer.
        auto cell = [&](f32x4 acc, const float* gb, const float* bia,
                        f32x4& cst, f16* hw) {
            #pragma unroll
            for (int r = 0; r < 4; ++r) {
                float own = acc[r];
                float v4  = __shfl_xor(own, 4);
                float v8  = __shfl_xor(own, 8);
                float v12 = __shfl_xor(own, 12);
                float ip = gid==0?own: gid==1?v4 : gid==2?v8 : v12;
                float fp = gid==0?v4 : gid==1?own: gid==2?v12: v8;
                float op = gid==0?v8 : gid==1?v12: gid==2?own: v4;
                float gp = gid==0?v12: gid==1?v8 : gid==2?v4 : own;
                float I = fsigm(ip + gb[0]);
                float F = fsigm(fp + gb[1] + bia[r]);
                float O = fsigm(op + gb[2]);
                float G = ftanh_(gp + gb[3]);
                float c = F * cst[r] + I * G;
                cst[r] = c;
                float h = O * ftanh_(c);
                if (n < 4) {
                    union { f16 hf; unsigned short us; } cv; cv.hf = (f16)h;
                    // write-through to LLC (sc0 sc1): never dirties L2, so the
                    // barrier needs no buffer_wbl2 anywhere.
                    __hip_atomic_store(
                        (unsigned short*)&hw[(size_t)(wg * 128 + mt * 16 + q * 4 + r) * 4 + n],
                        cv.us, __ATOMIC_RELAXED, __HIP_MEMORY_SCOPE_AGENT);
                }
            }
        };
        if (do_l0) cell(g0acc, gb0, bia0, c0v, h0w);
        if (do_l1) cell(g1acc, gb1, bia1, c1v, h1w);

        // ---- fence-light grid barrier (identical to round-4) ----
        // __syncthreads drains every wave's WT stores (vmcnt 0) before tid0
        // signals arrival, so all h-state is at the LLC coherence point.
        __syncthreads();
        if (tid == 0) {
            const unsigned tgt = epoch + 1u;
            // arrive on my group's line (8 parallel lines, 32 RMWs each)
            __hip_atomic_fetch_add(garr, 1u, __ATOMIC_RELAXED,
                                   __HIP_MEMORY_SCOPE_AGENT);
            // group leaders aggregate into the global counter
            if (glead) {
                while (__hip_atomic_load(garr, __ATOMIC_RELAXED,
                                         __HIP_MEMORY_SCOPE_AGENT) < 32u * tgt)
                    __builtin_amdgcn_s_sleep(1);
                __hip_atomic_fetch_add(sync, 32u, __ATOMIC_RELAXED,
                                       __HIP_MEMORY_SCOPE_AGENT);
            }
            if (lead) {
                while (__hip_atomic_load(sync, __ATOMIC_RELAXED,
                                         __HIP_MEMORY_SCOPE_AGENT) < NWG * tgt)
                    __builtin_amdgcn_s_sleep(1);
                // one L2(+L1) invalidate for the whole XCD, completed before
                // the release flag is published.  (After the poll: no other
                // WG on this XCD is still reading this step's data.)
                asm volatile("buffer_inv sc1\n\ts_waitcnt vmcnt(0)" ::: "memory");
                __hip_atomic_store(relp, tgt, __ATOMIC_RELAXED,
                                   __HIP_MEMORY_SCOPE_AGENT);
            } else {
                while (__hip_atomic_load(relp, __ATOMIC_RELAXED,
                                         __HIP_MEMORY_SCOPE_AGENT) < tgt)
                    __builtin_amdgcn_s_sleep(1);
                // per-CU L1 invalidate only; leader already cleaned our L2.
                asm volatile("buffer_inv\n\ts_waitcnt vmcnt(0)" ::: "memory");
            }
        }
        epoch++;
        __syncthreads();
    }

    // ---- fc head: out[b] = fcW . h1(511)[b] + fcb ----
    if (blockIdx.x < Bd) {
        int b = blockIdx.x;
        const f16* hf = h1buf + S;                    // parity 1 holds h1(511)
        int k = tid * 2;                              // k, k+1 share a kblk
        int idx = (((k >> 2) * 128 + b) << 2) + (k & 3);
        float sum = (float)hf[idx] * fcW[k] + (float)hf[idx + 1] * fcW[k + 1];
        #pragma unroll
        for (int off = 32; off > 0; off >>= 1) sum += __shfl_down(sum, off);
        float* red = xchg;
        if (lane == 0) red[w] = sum;
        __syncthreads();
        if (tid == 0) {
            float t = 0.f;
            #pragma unroll
            for (int i = 0; i < 8; ++i) t += red[i];
            out[b] = t + fcb[0];
        }
    }
}

// ---------------------------------------------------------------------------
extern "C" void kernel_launch(void* const* d_in, const int* in_sizes, int n_in,
                              void* d_out, int out_size, void* d_ws, size_t ws_size,
                              hipStream_t stream) {
    const float* x        = (const float*)d_in[0];
    const float* boundary = (const float*)d_in[1];
    const float* Wx0      = (const float*)d_in[2];
    const float* bx0      = (const float*)d_in[3];
    const float* Uh0      = (const float*)d_in[4];
    const float* bh0      = (const float*)d_in[5];
    const float* Wb0      = (const float*)d_in[6];
    const float* bb0      = (const float*)d_in[7];
    const float* Wx1      = (const float*)d_in[8];
    const float* bx1      = (const float*)d_in[9];
    const float* Uh1      = (const float*)d_in[10];
    const float* bh1      = (const float*)d_in[11];
    const float* Wb1      = (const float*)d_in[12];
    const float* bb1      = (const float*)d_in[13];
    const float* fcW      = (const float*)d_in[14];
    const float* fcb      = (const float*)d_in[15];
    float* out = (float*)d_out;

    // workspace layout (bytes)
    char* ws = (char*)d_ws;
    f16*   xT    = (f16*)(ws);                       // 8,388,608 B
    f16*   h0buf = (f16*)(ws + 8388608);             //   524,288 B (2 parities)
    f16*   h1buf = (f16*)(ws + 8912896);             //   524,288 B
    float* bi0   = (float*)(ws + 9437184);           //   524,288 B
    float* bi1   = (float*)(ws + 9961472);           //   524,288 B
    unsigned int* sync = (unsigned int*)(ws + 10485760);  // 2,560 B sync block

    init_state<<<256, 512, 0, stream>>>(boundary, Wb0, bb0, Wb1, bb1,
                                        bi0, bi1, h0buf, h1buf, sync);
    xpose<<<8192, 512, 0, stream>>>(x, xT);

    void* args[] = {
        (void*)&xT, (void*)&h0buf, (void*)&h1buf, (void*)&bi0, (void*)&bi1,
        (void*)&Wx0, (void*)&bx0, (void*)&Uh0, (void*)&bh0,
        (void*)&Wx1, (void*)&bx1, (void*)&Uh1, (void*)&bh1,
        (void*)&fcW, (void*)&fcb, (void*)&out, (void*)&sync
    };
    hipLaunchCooperativeKernel((void*)lstm_persist, dim3(NWG), dim3(NTHR),
                               args, 0, stream);
}

// Round 6
// 11000.981 us; speedup vs baseline: 1.8336x; 1.8336x over previous
//
#include <hip/hip_runtime.h>
#include <math.h>

// ---------------------------------------------------------------------------
// Persistent-RNN LSTM for MI355X.
//   B=128, T=512, IN=64, H=1024, 2 layers, head OUT=1 on last step.
// Design:
//  - 256 WGs x 512 threads (8 waves), cooperative launch, 1 WG/CU.
//  - Weights f16-resident: layer0 [Uh0|Wx0] slice (16 rows x 1088) in LDS
//    (35 KB); layer1 [Wx1/Uh1] slice in VGPRs (32 half8 frags/lane = 128 VGPR).
//  - WG owns 4 h-columns => 16 gate rows (order i0..3,f0..3,o0..3,g0..3).
//  - mfma_f32_16x16x32_f16: A = h-state frags from global (f16), B = weights.
//  - ROW-MAJOR h layout (round-4 verified).  NOTE: round-5's blocked
//    h[kblk][batch][4] layout regressed FETCH_SIZE 29x (true-HBM reads,
//    62 MB/step) and nearly doubled dur — do not reintroduce.
//  - Software pipeline: iter s computes layer1(s) AND layer0(s+1), sharing
//    h0(s) fragment loads. 513 grid barriers total.
//  - Layer1 K=2048 split: waves 0-3 k<1024 (A=h0), waves 4-7 k>=1024 (A=h1);
//    partials exchanged via LDS. Waves 0-3 also compute BOTH layer0 tiles
//    (fused with their h0 loads); acc for tile 2p+1 handed to wave 4+p.
//  - Cell math fp32 with fast __expf/__fdividef sigmoid/tanh (round-5
//    harness-verified numerics, absmax unchanged); c-state in registers;
//    gate gather via shfl_xor(4,8,12).
//  - Fence-light grid barrier: BYTE-IDENTICAL to the round-4 kernel that
//    passed (WT h-stores sc0 sc1; static arrival tree garr[wg>>5], group
//    leaders aggregate 32 into global; XCD leaders poll global, buffer_inv
//    sc1 AFTER the poll, release per-XCD flag; followers poll flag then L1
//    buffer_inv).
// ---------------------------------------------------------------------------

#define Hd 1024
#define Bd 128
#define Td 512
#define INd 64
#define NWG 256
#define NTHR 512

typedef _Float16 f16;
typedef _Float16 half8 __attribute__((ext_vector_type(8)));
typedef float f32x4 __attribute__((ext_vector_type(4)));

// sync[] layout (uint index):
//   [0]           : global step counter (group leaders add 32; target 256*ep)
//   [32 + 32*g]   : per-group arrival counter (monotonic), g = wg>>5
//   [288 + 32*x]  : per-XCD release flag (epoch), x = physical XCD
//   [608 + x]     : per-XCD leader-election counter
// zero first 640 uints.

__device__ __forceinline__ float fsigm(float x) {
    // 1/(1+e^-x); exp overflow -> inf -> divide -> 0 (correct saturation)
    return __fdividef(1.f, 1.f + __expf(-x));
}
__device__ __forceinline__ float ftanh_(float x) {
    // tanh(x) = 1 - 2/(e^(2x)+1); both +-inf limits correct
    return 1.f - __fdividef(2.f, 1.f + __expf(2.f * x));
}

// ---------------- init: bi0/bi1, zero h buffers, zero sync ----------------
__global__ __launch_bounds__(512) void init_state(
    const float* __restrict__ bnd, const float* __restrict__ Wb0,
    const float* __restrict__ bb0, const float* __restrict__ Wb1,
    const float* __restrict__ bb1,
    float* __restrict__ bi0, float* __restrict__ bi1,
    f16* __restrict__ h0buf, f16* __restrict__ h1buf,
    unsigned int* __restrict__ sync)
{
    int idx = blockIdx.x * 512 + threadIdx.x;   // [0, B*H)
    int b = idx >> 10;
    int h = idx & 1023;
    float b0v = bnd[b * 2 + 0], b1v = bnd[b * 2 + 1];
    bi0[idx] = b0v * Wb0[h * 2 + 0] + b1v * Wb0[h * 2 + 1] + bb0[h];
    bi1[idx] = b0v * Wb1[h * 2 + 0] + b1v * Wb1[h * 2 + 1] + bb1[h];
    h0buf[idx] = (f16)0.f;  h0buf[idx + Bd * Hd] = (f16)0.f;
    h1buf[idx] = (f16)0.f;  h1buf[idx + Bd * Hd] = (f16)0.f;
    if (idx < 640) sync[idx] = 0u;
}

// ---------------- transpose x [B,T,IN] f32 -> xT [T,B,IN] f16 ----------------
__global__ __launch_bounds__(512) void xpose(
    const float* __restrict__ x, f16* __restrict__ xT)
{
    int idx = blockIdx.x * 512 + threadIdx.x;   // [0, B*T*IN)
    int b = idx >> 15;           // T*IN = 32768
    int t = (idx >> 6) & 511;
    int i = idx & 63;
    xT[((size_t)t * Bd + b) * INd + i] = (f16)x[idx];
}

// ---------------- persistent LSTM ----------------
__global__ __launch_bounds__(NTHR, 2) void lstm_persist(
    const f16* __restrict__ xT,
    f16* __restrict__ h0buf, f16* __restrict__ h1buf,
    const float* __restrict__ bi0, const float* __restrict__ bi1,
    const float* __restrict__ Wx0, const float* __restrict__ bx0,
    const float* __restrict__ Uh0, const float* __restrict__ bh0,
    const float* __restrict__ Wx1, const float* __restrict__ bx1,
    const float* __restrict__ Uh1, const float* __restrict__ bh1,
    const float* __restrict__ fcW, const float* __restrict__ fcb,
    float* __restrict__ out, unsigned int* __restrict__ sync)
{
    const int tid  = threadIdx.x;
    const int w    = tid >> 6;        // wave 0..7
    const int lane = tid & 63;
    const int n    = lane & 15;       // frag col (gate-col within WG)
    const int q    = lane >> 4;       // 0..3
    const int wg   = blockIdx.x;
    const int c0wg = wg * 4;          // h-column base of this WG
    const int hcol = c0wg + (n & 3);
    const int gid  = n >> 2;          // gate group of my frag col
    const bool lowhalf = (w < 4);
    const int p    = lowhalf ? w : (w - 4);
    const int mt   = lowhalf ? 2 * p : 2 * p + 1;  // my cell tile (both layers)
    const size_t S = (size_t)Bd * Hd;

    __shared__ f16 B0[16 * 1096];       // layer0 weights [16 rows][1088+8 pad]
    __shared__ float xchg[3072];        // 12 exchange slots x 256 floats

    // ---- static arrival group + physical-XCD leader election ----
    const bool glead = ((wg & 31) == 0);           // logical group leader
    unsigned int* garr = sync + 32 + 32 * (wg >> 5);
    int  xcd  = 0;
    bool lead = false;                              // physical-XCD inv leader
    unsigned int* relp = nullptr;
    if (tid == 0) {
        asm volatile("s_getreg_b32 %0, hwreg(HW_REG_XCC_ID)" : "=s"(xcd));
        xcd &= 7;
        unsigned r = __hip_atomic_fetch_add(&sync[608 + xcd], 1u,
                         __ATOMIC_RELAXED, __HIP_MEMORY_SCOPE_AGENT);
        lead = (r == 0u);
        relp = sync + 288 + 32 * xcd;
    }

    // ---- fill B0 (f32 -> f16): row nr -> global gate row ----
    {
        int nr = tid >> 5;              // 0..15
        int gr = (nr >> 2) * Hd + c0wg + (nr & 3);
        for (int k = tid & 31; k < 1088; k += 32) {
            float v = (k < Hd) ? Uh0[(size_t)gr * Hd + k]
                               : Wx0[(size_t)gr * INd + (k - Hd)];
            B0[nr * 1096 + k] = (f16)v;
        }
    }

    // ---- preload layer1 B frags into VGPRs (my k-half) ----
    half8 b1f[32];
    {
        const float* Wsrc = lowhalf ? Wx1 : Uh1;
        int gr = gid * Hd + c0wg + (n & 3);
        const float* rp = Wsrc + (size_t)gr * Hd + q * 8;
        #pragma unroll
        for (int kk = 0; kk < 32; ++kk) {
            half8 hv;
            #pragma unroll
            for (int j = 0; j < 8; ++j) hv[j] = (f16)rp[kk * 32 + j];
            b1f[kk] = hv;
        }
    }

    // ---- per-lane biases & c-state ----
    float gb0[4], gb1[4], bia0[4], bia1[4];
    #pragma unroll
    for (int g = 0; g < 4; ++g) {
        gb0[g] = bx0[g * Hd + hcol] + bh0[g * Hd + hcol];
        gb1[g] = bx1[g * Hd + hcol] + bh1[g * Hd + hcol];
    }
    #pragma unroll
    for (int r = 0; r < 4; ++r) {
        int row = mt * 16 + q * 4 + r;
        bia0[r] = bi0[row * Hd + hcol];
        bia1[r] = bi1[row * Hd + hcol];
    }
    f32x4 c0v = {0.f, 0.f, 0.f, 0.f};
    f32x4 c1v = {0.f, 0.f, 0.f, 0.f};

    __syncthreads();   // B0 ready

    unsigned epoch = 0;

    for (int s = -1; s <= 511; ++s) {
        const bool do_l0 = (s < 511);
        const bool do_l1 = (s >= 0);
        const int pr = s & 1;                 // s=-1 -> 1
        const f16* h0r = h0buf + (size_t)pr * S;
        f16*       h0w = h0buf + (size_t)(1 - pr) * S;
        const f16* h1r = h1buf + (size_t)(1 - pr) * S;
        f16*       h1w = h1buf + (size_t)pr * S;

        f32x4 a0a = {0.f,0.f,0.f,0.f}, a0b = {0.f,0.f,0.f,0.f};
        f32x4 a1a = {0.f,0.f,0.f,0.f}, a1b = {0.f,0.f,0.f,0.f};

        if (lowhalf) {
            const half8* pA0 = (const half8*)(h0r + (size_t)(2*p*16 + n) * Hd + q*8);
            const half8* pA1 = (const half8*)(h0r + (size_t)((2*p+1)*16 + n) * Hd + q*8);
            const half8* pB  = (const half8*)(&B0[n * 1096 + q * 8]);
            if (do_l0 && do_l1) {
                #pragma unroll
                for (int kk = 0; kk < 32; ++kk) {
                    half8 A0 = pA0[kk*4], A1 = pA1[kk*4], Bl = pB[kk*4];
                    a0a = __builtin_amdgcn_mfma_f32_16x16x32_f16(A0, Bl, a0a, 0,0,0);
                    a0b = __builtin_amdgcn_mfma_f32_16x16x32_f16(A1, Bl, a0b, 0,0,0);
                    a1a = __builtin_amdgcn_mfma_f32_16x16x32_f16(A0, b1f[kk], a1a, 0,0,0);
                    a1b = __builtin_amdgcn_mfma_f32_16x16x32_f16(A1, b1f[kk], a1b, 0,0,0);
                }
            } else if (do_l0) {          // s == -1
                #pragma unroll
                for (int kk = 0; kk < 32; ++kk) {
                    half8 A0 = pA0[kk*4], A1 = pA1[kk*4], Bl = pB[kk*4];
                    a0a = __builtin_amdgcn_mfma_f32_16x16x32_f16(A0, Bl, a0a, 0,0,0);
                    a0b = __builtin_amdgcn_mfma_f32_16x16x32_f16(A1, Bl, a0b, 0,0,0);
                }
            } else {                     // s == 511
                #pragma unroll
                for (int kk = 0; kk < 32; ++kk) {
                    half8 A0 = pA0[kk*4], A1 = pA1[kk*4];
                    a1a = __builtin_amdgcn_mfma_f32_16x16x32_f16(A0, b1f[kk], a1a, 0,0,0);
                    a1b = __builtin_amdgcn_mfma_f32_16x16x32_f16(A1, b1f[kk], a1b, 0,0,0);
                }
            }
            if (do_l0) {                 // x-projection chunks (k = 1024..1087)
                const f16* xt = xT + (size_t)(s + 1) * Bd * INd;
                const half8* pX0 = (const half8*)(xt + (size_t)(2*p*16 + n) * INd + q*8);
                const half8* pX1 = (const half8*)(xt + (size_t)((2*p+1)*16 + n) * INd + q*8);
                #pragma unroll
                for (int kk = 0; kk < 2; ++kk) {
                    half8 Bl = pB[(32 + kk) * 4];
                    a0a = __builtin_amdgcn_mfma_f32_16x16x32_f16(pX0[kk*4], Bl, a0a, 0,0,0);
                    a0b = __builtin_amdgcn_mfma_f32_16x16x32_f16(pX1[kk*4], Bl, a0b, 0,0,0);
                }
            }
        } else if (do_l1) {              // waves 4-7: layer1 k-half 1 (A = h1)
            const half8* pH1a = (const half8*)(h1r + (size_t)(2*p*16 + n) * Hd + q*8);
            const half8* pH1b = (const half8*)(h1r + (size_t)((2*p+1)*16 + n) * Hd + q*8);
            #pragma unroll
            for (int kk = 0; kk < 32; ++kk) {
                half8 A0 = pH1a[kk*4], A1 = pH1b[kk*4];
                a1a = __builtin_amdgcn_mfma_f32_16x16x32_f16(A0, b1f[kk], a1a, 0,0,0);
                a1b = __builtin_amdgcn_mfma_f32_16x16x32_f16(A1, b1f[kk], a1b, 0,0,0);
            }
        }

        // ---- exchange partials via LDS ----
        float* slotA = xchg;              // layer0 tile 2p+1 (from wave p)
        float* slotB = xchg + 1024;       // layer1 tile 2p+1 k-half0 (from wave p)
        float* slotC = xchg + 2048;       // layer1 tile 2p   k-half1 (from wave 4+p)
        if (lowhalf) {
            if (do_l0) *(f32x4*)&slotA[p * 256 + lane * 4] = a0b;
            if (do_l1) *(f32x4*)&slotB[p * 256 + lane * 4] = a1b;
        } else {
            if (do_l1) *(f32x4*)&slotC[p * 256 + lane * 4] = a1a;
        }
        __syncthreads();

        f32x4 g0acc, g1acc;
        if (lowhalf) {
            g0acc = a0a;
            if (do_l1) g1acc = a1a + *(const f32x4*)&slotC[p * 256 + lane * 4];
        } else {
            if (do_l0) g0acc = *(const f32x4*)&slotA[p * 256 + lane * 4];
            if (do_l1) g1acc = a1b + *(const f32x4*)&slotB[p * 256 + lane * 4];
        }

        // ---- cell updates (fp32, fast sigmoid/tanh), write h (f16 WT) ----
        auto cell = [&](f32x4 acc, const float* gb, const float* bia,
                        f32x4& cst, f16* hw) {
            #pragma unroll
            for (int r = 0; r < 4; ++r) {
                float own = acc[r];
                float v4  = __shfl_xor(own, 4);
                float v8  = __shfl_xor(own, 8);
                float v12 = __shfl_xor(own, 12);
                float ip = gid==0?own: gid==1?v4 : gid==2?v8 : v12;
                float fp = gid==0?v4 : gid==1?own: gid==2?v12: v8;
                float op = gid==0?v8 : gid==1?v12: gid==2?own: v4;
                float gp = gid==0?v12: gid==1?v8 : gid==2?v4 : own;
                float I = fsigm(ip + gb[0]);
                float F = fsigm(fp + gb[1] + bia[r]);
                float O = fsigm(op + gb[2]);
                float G = ftanh_(gp + gb[3]);
                float c = F * cst[r] + I * G;
                cst[r] = c;
                float h = O * ftanh_(c);
                if (n < 4) {
                    union { f16 hf; unsigned short us; } cv; cv.hf = (f16)h;
                    // write-through to LLC (sc0 sc1): never dirties L2, so the
                    // barrier needs no buffer_wbl2 anywhere.
                    __hip_atomic_store(
                        (unsigned short*)&hw[(size_t)(mt * 16 + q * 4 + r) * Hd + c0wg + n],
                        cv.us, __ATOMIC_RELAXED, __HIP_MEMORY_SCOPE_AGENT);
                }
            }
        };
        if (do_l0) cell(g0acc, gb0, bia0, c0v, h0w);
        if (do_l1) cell(g1acc, gb1, bia1, c1v, h1w);

        // ---- fence-light grid barrier (identical to round-4) ----
        // __syncthreads drains every wave's WT stores (vmcnt 0) before tid0
        // signals arrival, so all h-state is at the LLC coherence point.
        __syncthreads();
        if (tid == 0) {
            const unsigned tgt = epoch + 1u;
            // arrive on my group's line (8 parallel lines, 32 RMWs each)
            __hip_atomic_fetch_add(garr, 1u, __ATOMIC_RELAXED,
                                   __HIP_MEMORY_SCOPE_AGENT);
            // group leaders aggregate into the global counter
            if (glead) {
                while (__hip_atomic_load(garr, __ATOMIC_RELAXED,
                                         __HIP_MEMORY_SCOPE_AGENT) < 32u * tgt)
                    __builtin_amdgcn_s_sleep(1);
                __hip_atomic_fetch_add(sync, 32u, __ATOMIC_RELAXED,
                                       __HIP_MEMORY_SCOPE_AGENT);
            }
            if (lead) {
                while (__hip_atomic_load(sync, __ATOMIC_RELAXED,
                                         __HIP_MEMORY_SCOPE_AGENT) < NWG * tgt)
                    __builtin_amdgcn_s_sleep(1);
                // one L2(+L1) invalidate for the whole XCD, completed before
                // the release flag is published.  (After the poll: no other
                // WG on this XCD is still reading this step's data.)
                asm volatile("buffer_inv sc1\n\ts_waitcnt vmcnt(0)" ::: "memory");
                __hip_atomic_store(relp, tgt, __ATOMIC_RELAXED,
                                   __HIP_MEMORY_SCOPE_AGENT);
            } else {
                while (__hip_atomic_load(relp, __ATOMIC_RELAXED,
                                         __HIP_MEMORY_SCOPE_AGENT) < tgt)
                    __builtin_amdgcn_s_sleep(1);
                // per-CU L1 invalidate only; leader already cleaned our L2.
                asm volatile("buffer_inv\n\ts_waitcnt vmcnt(0)" ::: "memory");
            }
        }
        epoch++;
        __syncthreads();
    }

    // ---- fc head: out[b] = fcW . h1(511)[b] + fcb ----
    if (blockIdx.x < Bd) {
        int b = blockIdx.x;
        const f16* hf = h1buf + S + (size_t)b * Hd;   // parity 1 holds h1(511)
        int k = tid * 2;
        float sum = (float)hf[k] * fcW[k] + (float)hf[k + 1] * fcW[k + 1];
        #pragma unroll
        for (int off = 32; off > 0; off >>= 1) sum += __shfl_down(sum, off);
        float* red = xchg;
        if (lane == 0) red[w] = sum;
        __syncthreads();
        if (tid == 0) {
            float t = 0.f;
            #pragma unroll
            for (int i = 0; i < 8; ++i) t += red[i];
            out[b] = t + fcb[0];
        }
    }
}

// ---------------------------------------------------------------------------
extern "C" void kernel_launch(void* const* d_in, const int* in_sizes, int n_in,
                              void* d_out, int out_size, void* d_ws, size_t ws_size,
                              hipStream_t stream) {
    const float* x        = (const float*)d_in[0];
    const float* boundary = (const float*)d_in[1];
    const float* Wx0      = (const float*)d_in[2];
    const float* bx0      = (const float*)d_in[3];
    const float* Uh0      = (const float*)d_in[4];
    const float* bh0      = (const float*)d_in[5];
    const float* Wb0      = (const float*)d_in[6];
    const float* bb0      = (const float*)d_in[7];
    const float* Wx1      = (const float*)d_in[8];
    const float* bx1      = (const float*)d_in[9];
    const float* Uh1      = (const float*)d_in[10];
    const float* bh1      = (const float*)d_in[11];
    const float* Wb1      = (const float*)d_in[12];
    const float* bb1      = (const float*)d_in[13];
    const float* fcW      = (const float*)d_in[14];
    const float* fcb      = (const float*)d_in[15];
    float* out = (float*)d_out;

    // workspace layout (bytes)
    char* ws = (char*)d_ws;
    f16*   xT    = (f16*)(ws);                       // 8,388,608 B
    f16*   h0buf = (f16*)(ws + 8388608);             //   524,288 B (2 parities)
    f16*   h1buf = (f16*)(ws + 8912896);             //   524,288 B
    float* bi0   = (float*)(ws + 9437184);           //   524,288 B
    float* bi1   = (float*)(ws + 9961472);           //   524,288 B
    unsigned int* sync = (unsigned int*)(ws + 10485760);  // 2,560 B sync block

    init_state<<<256, 512, 0, stream>>>(boundary, Wb0, bb0, Wb1, bb1,
                                        bi0, bi1, h0buf, h1buf, sync);
    xpose<<<8192, 512, 0, stream>>>(x, xT);

    void* args[] = {
        (void*)&xT, (void*)&h0buf, (void*)&h1buf, (void*)&bi0, (void*)&bi1,
        (void*)&Wx0, (void*)&bx0, (void*)&Uh0, (void*)&bh0,
        (void*)&Wx1, (void*)&bx1, (void*)&Uh1, (void*)&bh1,
        (void*)&fcW, (void*)&fcb, (void*)&out, (void*)&sync
    };
    hipLaunchCooperativeKernel((void*)lstm_persist, dim3(NWG), dim3(NTHR),
                               args, 0, stream);
}

// Round 7
// 10748.888 us; speedup vs baseline: 1.8766x; 1.0235x over previous
//
#include <hip/hip_runtime.h>
#include <math.h>

// ---------------------------------------------------------------------------
// Persistent-RNN LSTM for MI355X.
//   B=128, T=512, IN=64, H=1024, 2 layers, head OUT=1 on last step.
// Design (round 7 re-tile):
//  - 256 WGs x 512 threads (8 waves), cooperative launch, 1 WG/CU.
//  - WG (gb = wg>>1, bh = wg&1) owns 8 h-cols [gb*8, gb*8+8) x 64 batch rows
//    [bh*64, bh*64+64) => 32 gate rows, HALF the batch.  Per-WG h reads
//    halve vs round-6 (256 KB vs 512 KB): 8 MB/XCD/step through L2.
//  - Gate-tile order: tile0 = [i(0..7), f(0..7)], tile1 = [o(0..7), g(0..7)].
//  - Weights resident: layer0 [Uh0|Wx0] 32 rows x 1088 f16 in LDS (70 KB);
//    layer1 64 half8 frags/lane (b1f0+b1f1 = 256 regs -> AGPR file).
//  - mfma_f32_16x16x32_f16: ONE A-frag load per kk feeds 4 MFMAs (l0 t0/t1 +
//    l1-khalf t0/t1).  Waves 0-3: A=h0 (l0 + l1 k<1024); waves 4-7: A=h1
//    (l1 k>=1024).  l0 needs NO LDS exchange; l1 partials exchanged (8 KB),
//    cell done by highhalf.  Cell gather = single shfl_xor(8) pair.
//  - Stores: 8 contiguous cols x 2B = 16B/row slivers (2x wider than round-6
//    -> half the memory-side line RMWs).  ROW-MAJOR h layout (round-5's
//    blocked layout regressed 29x FETCH — do not reintroduce).
//  - Cell math fp32, fast __expf/__fdividef sigmoid/tanh (round-5/6 verified).
//  - Fence-light grid barrier: BYTE-IDENTICAL to round-4/6 verified kernel
//    (WT h-stores sc0 sc1; static arrival tree garr[wg>>5]; group leaders
//    aggregate 32 into global; XCD leaders poll global, buffer_inv sc1 AFTER
//    poll, release per-XCD flag; followers poll flag then L1 buffer_inv).
// ---------------------------------------------------------------------------

#define Hd 1024
#define Bd 128
#define Td 512
#define INd 64
#define NWG 256
#define NTHR 512

typedef _Float16 f16;
typedef _Float16 half8 __attribute__((ext_vector_type(8)));
typedef float f32x4 __attribute__((ext_vector_type(4)));

// sync[] layout (uint index):
//   [0]           : global step counter (group leaders add 32; target 256*ep)
//   [32 + 32*g]   : per-group arrival counter (monotonic), g = wg>>5
//   [288 + 32*x]  : per-XCD release flag (epoch), x = physical XCD
//   [608 + x]     : per-XCD leader-election counter
// zero first 640 uints.

__device__ __forceinline__ float fsigm(float x) {
    return __fdividef(1.f, 1.f + __expf(-x));
}
__device__ __forceinline__ float ftanh_(float x) {
    return 1.f - __fdividef(2.f, 1.f + __expf(2.f * x));
}

// ---------------- init: bi0/bi1, zero h buffers, zero sync ----------------
__global__ __launch_bounds__(512) void init_state(
    const float* __restrict__ bnd, const float* __restrict__ Wb0,
    const float* __restrict__ bb0, const float* __restrict__ Wb1,
    const float* __restrict__ bb1,
    float* __restrict__ bi0, float* __restrict__ bi1,
    f16* __restrict__ h0buf, f16* __restrict__ h1buf,
    unsigned int* __restrict__ sync)
{
    int idx = blockIdx.x * 512 + threadIdx.x;   // [0, B*H)
    int b = idx >> 10;
    int h = idx & 1023;
    float b0v = bnd[b * 2 + 0], b1v = bnd[b * 2 + 1];
    bi0[idx] = b0v * Wb0[h * 2 + 0] + b1v * Wb0[h * 2 + 1] + bb0[h];
    bi1[idx] = b0v * Wb1[h * 2 + 0] + b1v * Wb1[h * 2 + 1] + bb1[h];
    h0buf[idx] = (f16)0.f;  h0buf[idx + Bd * Hd] = (f16)0.f;
    h1buf[idx] = (f16)0.f;  h1buf[idx + Bd * Hd] = (f16)0.f;
    if (idx < 640) sync[idx] = 0u;
}

// ---------------- transpose x [B,T,IN] f32 -> xT [T,B,IN] f16 ----------------
__global__ __launch_bounds__(512) void xpose(
    const float* __restrict__ x, f16* __restrict__ xT)
{
    int idx = blockIdx.x * 512 + threadIdx.x;   // [0, B*T*IN)
    int b = idx >> 15;           // T*IN = 32768
    int t = (idx >> 6) & 511;
    int i = idx & 63;
    xT[((size_t)t * Bd + b) * INd + i] = (f16)x[idx];
}

// ---------------- persistent LSTM ----------------
__global__ __launch_bounds__(NTHR, 2) void lstm_persist(
    const f16* __restrict__ xT,
    f16* __restrict__ h0buf, f16* __restrict__ h1buf,
    const float* __restrict__ bi0, const float* __restrict__ bi1,
    const float* __restrict__ Wx0, const float* __restrict__ bx0,
    const float* __restrict__ Uh0, const float* __restrict__ bh0,
    const float* __restrict__ Wx1, const float* __restrict__ bx1,
    const float* __restrict__ Uh1, const float* __restrict__ bh1,
    const float* __restrict__ fcW, const float* __restrict__ fcb,
    float* __restrict__ out, unsigned int* __restrict__ sync)
{
    const int tid  = threadIdx.x;
    const int w    = tid >> 6;        // wave 0..7
    const int lane = tid & 63;
    const int n    = lane & 15;       // frag col within tile
    const int q    = lane >> 4;       // 0..3
    const int wg   = blockIdx.x;
    const int gb   = wg >> 1;         // gate-block 0..127 (8 h-cols)
    const int bh   = wg & 1;          // batch half
    const int hc0  = gb * 8;          // h-col base
    const int hcol = hc0 + (n & 7);   // this lane's cell column
    const bool lowhalf = (w < 4);
    const int p    = lowhalf ? w : (w - 4);
    const int bt   = bh * 64 + p * 16;  // batch-tile base row (per wave)
    const size_t S = (size_t)Bd * Hd;

    __shared__ f16 B0[32 * 1096];       // layer0 weights [32 rows][1088+8 pad]
    __shared__ float xchg[2048];        // l1 exchange: 4 waves x 2 tiles x 256

    // ---- static arrival group + physical-XCD leader election ----
    const bool glead = ((wg & 31) == 0);
    unsigned int* garr = sync + 32 + 32 * (wg >> 5);
    int  xcd  = 0;
    bool lead = false;
    unsigned int* relp = nullptr;
    if (tid == 0) {
        asm volatile("s_getreg_b32 %0, hwreg(HW_REG_XCC_ID)" : "=s"(xcd));
        xcd &= 7;
        unsigned r = __hip_atomic_fetch_add(&sync[608 + xcd], 1u,
                         __ATOMIC_RELAXED, __HIP_MEMORY_SCOPE_AGENT);
        lead = (r == 0u);
        relp = sync + 288 + 32 * xcd;
    }

    // ---- fill B0 (f32 -> f16): row nr -> global gate row ----
    // nr in [0,32): tile t = nr>>4, np = nr&15, gate = t*2 + (np>>3), col np&7
    {
        int nr = tid >> 4;              // 0..31
        int t  = nr >> 4, np = nr & 15;
        int gr = (t * 2 + (np >> 3)) * Hd + hc0 + (np & 7);
        for (int k = tid & 15; k < 1088; k += 16) {
            float v = (k < Hd) ? Uh0[(size_t)gr * Hd + k]
                               : Wx0[(size_t)gr * INd + (k - Hd)];
            B0[nr * 1096 + k] = (f16)v;
        }
    }

    // ---- preload layer1 B frags (both tiles) into regs (my k-half) ----
    half8 b1f0[32], b1f1[32];
    {
        const float* Wsrc = lowhalf ? Wx1 : Uh1;
        int gr0 = (0 + (n >> 3)) * Hd + hcol;    // tile0: i / f row
        int gr1 = (2 + (n >> 3)) * Hd + hcol;    // tile1: o / g row
        const float* rp0 = Wsrc + (size_t)gr0 * Hd + q * 8;
        const float* rp1 = Wsrc + (size_t)gr1 * Hd + q * 8;
        #pragma unroll
        for (int kk = 0; kk < 32; ++kk) {
            half8 h0v, h1v;
            #pragma unroll
            for (int j = 0; j < 8; ++j) {
                h0v[j] = (f16)rp0[kk * 32 + j];
                h1v[j] = (f16)rp1[kk * 32 + j];
            }
            b1f0[kk] = h0v;
            b1f1[kk] = h1v;
        }
    }

    // ---- per-lane biases & c-state ----
    float gb0[4], gb1[4], bia0[4], bia1[4];
    #pragma unroll
    for (int g = 0; g < 4; ++g) {
        gb0[g] = bx0[g * Hd + hcol] + bh0[g * Hd + hcol];
        gb1[g] = bx1[g * Hd + hcol] + bh1[g * Hd + hcol];
    }
    #pragma unroll
    for (int r = 0; r < 4; ++r) {
        int row = bt + q * 4 + r;
        bia0[r] = bi0[(size_t)row * Hd + hcol];
        bia1[r] = bi1[(size_t)row * Hd + hcol];
    }
    f32x4 c0v = {0.f, 0.f, 0.f, 0.f};
    f32x4 c1v = {0.f, 0.f, 0.f, 0.f};

    __syncthreads();   // B0 ready

    unsigned epoch = 0;

    for (int s = -1; s <= 511; ++s) {
        const bool do_l0 = (s < 511);
        const bool do_l1 = (s >= 0);
        const int pr = s & 1;                 // s=-1 -> 1
        const f16* h0r = h0buf + (size_t)pr * S;
        f16*       h0w = h0buf + (size_t)(1 - pr) * S;
        const f16* h1r = h1buf + (size_t)(1 - pr) * S;
        f16*       h1w = h1buf + (size_t)pr * S;

        f32x4 a0a = {0.f,0.f,0.f,0.f}, a0b = {0.f,0.f,0.f,0.f};
        f32x4 a1a = {0.f,0.f,0.f,0.f}, a1b = {0.f,0.f,0.f,0.f};

        if (lowhalf) {
            const half8* pA  = (const half8*)(h0r + (size_t)(bt + n) * Hd + q*8);
            const half8* pB0t = (const half8*)(&B0[n        * 1096 + q * 8]);
            const half8* pB1t = (const half8*)(&B0[(16 + n) * 1096 + q * 8]);
            if (do_l0 && do_l1) {
                #pragma unroll
                for (int kk = 0; kk < 32; ++kk) {
                    half8 A = pA[kk*4];
                    a0a = __builtin_amdgcn_mfma_f32_16x16x32_f16(A, pB0t[kk*4], a0a, 0,0,0);
                    a0b = __builtin_amdgcn_mfma_f32_16x16x32_f16(A, pB1t[kk*4], a0b, 0,0,0);
                    a1a = __builtin_amdgcn_mfma_f32_16x16x32_f16(A, b1f0[kk], a1a, 0,0,0);
                    a1b = __builtin_amdgcn_mfma_f32_16x16x32_f16(A, b1f1[kk], a1b, 0,0,0);
                }
            } else if (do_l0) {          // s == -1
                #pragma unroll
                for (int kk = 0; kk < 32; ++kk) {
                    half8 A = pA[kk*4];
                    a0a = __builtin_amdgcn_mfma_f32_16x16x32_f16(A, pB0t[kk*4], a0a, 0,0,0);
                    a0b = __builtin_amdgcn_mfma_f32_16x16x32_f16(A, pB1t[kk*4], a0b, 0,0,0);
                }
            } else {                     // s == 511: l1-khalf0 only
                #pragma unroll
                for (int kk = 0; kk < 32; ++kk) {
                    half8 A = pA[kk*4];
                    a1a = __builtin_amdgcn_mfma_f32_16x16x32_f16(A, b1f0[kk], a1a, 0,0,0);
                    a1b = __builtin_amdgcn_mfma_f32_16x16x32_f16(A, b1f1[kk], a1b, 0,0,0);
                }
            }
            if (do_l0) {                 // x-projection chunks (k = 1024..1087)
                const f16* xt = xT + (size_t)(s + 1) * Bd * INd;
                const half8* pX = (const half8*)(xt + (size_t)(bt + n) * INd + q*8);
                #pragma unroll
                for (int kk = 0; kk < 2; ++kk) {
                    half8 X = pX[kk*4];
                    a0a = __builtin_amdgcn_mfma_f32_16x16x32_f16(X, pB0t[(32+kk)*4], a0a, 0,0,0);
                    a0b = __builtin_amdgcn_mfma_f32_16x16x32_f16(X, pB1t[(32+kk)*4], a0b, 0,0,0);
                }
            }
        } else if (do_l1) {              // waves 4-7: layer1 k-half 1 (A = h1)
            const half8* pH = (const half8*)(h1r + (size_t)(bt + n) * Hd + q*8);
            #pragma unroll
            for (int kk = 0; kk < 32; ++kk) {
                half8 A = pH[kk*4];
                a1a = __builtin_amdgcn_mfma_f32_16x16x32_f16(A, b1f0[kk], a1a, 0,0,0);
                a1b = __builtin_amdgcn_mfma_f32_16x16x32_f16(A, b1f1[kk], a1b, 0,0,0);
            }
        }

        // ---- exchange l1 khalf0 partials: lowhalf wave p -> highhalf wave p ----
        if (lowhalf && do_l1) {
            *(f32x4*)&xchg[p * 512 +       lane * 4] = a1a;
            *(f32x4*)&xchg[p * 512 + 256 + lane * 4] = a1b;
        }
        __syncthreads();
        f32x4 g1a, g1b;
        if (!lowhalf && do_l1) {
            g1a = a1a + *(const f32x4*)&xchg[p * 512 +       lane * 4];
            g1b = a1b + *(const f32x4*)&xchg[p * 512 + 256 + lane * 4];
        }

        // ---- cell update (fp32, fast sigmoid/tanh), write h (f16 WT) ----
        // accA = tile0 (i|f), accB = tile1 (o|g).  Lane n<8: own=i,o;
        // xor8 partner holds f,g for the same column.  Lanes n>=8 compute
        // redundantly and don't store.  Store = 8 contiguous cols x 2B.
        auto cell = [&](f32x4 accA, f32x4 accB, const float* gbx,
                        const float* bia, f32x4& cst, f16* hw) {
            #pragma unroll
            for (int r = 0; r < 4; ++r) {
                float t0  = accA[r];
                float t1  = accB[r];
                float t0x = __shfl_xor(t0, 8);
                float t1x = __shfl_xor(t1, 8);
                float I = fsigm(t0  + gbx[0]);
                float F = fsigm(t0x + gbx[1] + bia[r]);
                float O = fsigm(t1  + gbx[2]);
                float G = ftanh_(t1x + gbx[3]);
                float c = F * cst[r] + I * G;
                cst[r] = c;
                float h = O * ftanh_(c);
                if (n < 8) {
                    union { f16 hf; unsigned short us; } cv; cv.hf = (f16)h;
                    // write-through to LLC (sc0 sc1): never dirties L2.
                    __hip_atomic_store(
                        (unsigned short*)&hw[(size_t)(bt + q * 4 + r) * Hd + hc0 + n],
                        cv.us, __ATOMIC_RELAXED, __HIP_MEMORY_SCOPE_AGENT);
                }
            }
        };
        if (lowhalf) { if (do_l0) cell(a0a, a0b, gb0, bia0, c0v, h0w); }
        else         { if (do_l1) cell(g1a, g1b, gb1, bia1, c1v, h1w); }

        // ---- fence-light grid barrier (identical to round-4/6) ----
        __syncthreads();
        if (tid == 0) {
            const unsigned tgt = epoch + 1u;
            __hip_atomic_fetch_add(garr, 1u, __ATOMIC_RELAXED,
                                   __HIP_MEMORY_SCOPE_AGENT);
            if (glead) {
                while (__hip_atomic_load(garr, __ATOMIC_RELAXED,
                                         __HIP_MEMORY_SCOPE_AGENT) < 32u * tgt)
                    __builtin_amdgcn_s_sleep(1);
                __hip_atomic_fetch_add(sync, 32u, __ATOMIC_RELAXED,
                                       __HIP_MEMORY_SCOPE_AGENT);
            }
            if (lead) {
                while (__hip_atomic_load(sync, __ATOMIC_RELAXED,
                                         __HIP_MEMORY_SCOPE_AGENT) < NWG * tgt)
                    __builtin_amdgcn_s_sleep(1);
                asm volatile("buffer_inv sc1\n\ts_waitcnt vmcnt(0)" ::: "memory");
                __hip_atomic_store(relp, tgt, __ATOMIC_RELAXED,
                                   __HIP_MEMORY_SCOPE_AGENT);
            } else {
                while (__hip_atomic_load(relp, __ATOMIC_RELAXED,
                                         __HIP_MEMORY_SCOPE_AGENT) < tgt)
                    __builtin_amdgcn_s_sleep(1);
                asm volatile("buffer_inv\n\ts_waitcnt vmcnt(0)" ::: "memory");
            }
        }
        epoch++;
        __syncthreads();
    }

    // ---- fc head: out[b] = fcW . h1(511)[b] + fcb ----
    if (blockIdx.x < Bd) {
        int b = blockIdx.x;
        const f16* hf = h1buf + S + (size_t)b * Hd;   // parity 1 holds h1(511)
        int k = tid * 2;
        float sum = (float)hf[k] * fcW[k] + (float)hf[k + 1] * fcW[k + 1];
        #pragma unroll
        for (int off = 32; off > 0; off >>= 1) sum += __shfl_down(sum, off);
        float* red = xchg;
        if (lane == 0) red[w] = sum;
        __syncthreads();
        if (tid == 0) {
            float t = 0.f;
            #pragma unroll
            for (int i = 0; i < 8; ++i) t += red[i];
            out[b] = t + fcb[0];
        }
    }
}

// ---------------------------------------------------------------------------
extern "C" void kernel_launch(void* const* d_in, const int* in_sizes, int n_in,
                              void* d_out, int out_size, void* d_ws, size_t ws_size,
                              hipStream_t stream) {
    const float* x        = (const float*)d_in[0];
    const float* boundary = (const float*)d_in[1];
    const float* Wx0      = (const float*)d_in[2];
    const float* bx0      = (const float*)d_in[3];
    const float* Uh0      = (const float*)d_in[4];
    const float* bh0      = (const float*)d_in[5];
    const float* Wb0      = (const float*)d_in[6];
    const float* bb0      = (const float*)d_in[7];
    const float* Wx1      = (const float*)d_in[8];
    const float* bx1      = (const float*)d_in[9];
    const float* Uh1      = (const float*)d_in[10];
    const float* bh1      = (const float*)d_in[11];
    const float* Wb1      = (const float*)d_in[12];
    const float* bb1      = (const float*)d_in[13];
    const float* fcW      = (const float*)d_in[14];
    const float* fcb      = (const float*)d_in[15];
    float* out = (float*)d_out;

    // workspace layout (bytes)
    char* ws = (char*)d_ws;
    f16*   xT    = (f16*)(ws);                       // 8,388,608 B
    f16*   h0buf = (f16*)(ws + 8388608);             //   524,288 B (2 parities)
    f16*   h1buf = (f16*)(ws + 8912896);             //   524,288 B
    float* bi0   = (float*)(ws + 9437184);           //   524,288 B
    float* bi1   = (float*)(ws + 9961472);           //   524,288 B
    unsigned int* sync = (unsigned int*)(ws + 10485760);  // 2,560 B sync block

    init_state<<<256, 512, 0, stream>>>(boundary, Wb0, bb0, Wb1, bb1,
                                        bi0, bi1, h0buf, h1buf, sync);
    xpose<<<8192, 512, 0, stream>>>(x, xT);

    void* args[] = {
        (void*)&xT, (void*)&h0buf, (void*)&h1buf, (void*)&bi0, (void*)&bi1,
        (void*)&Wx0, (void*)&bx0, (void*)&Uh0, (void*)&bh0,
        (void*)&Wx1, (void*)&bx1, (void*)&Uh1, (void*)&bh1,
        (void*)&fcW, (void*)&fcb, (void*)&out, (void*)&sync
    };
    hipLaunchCooperativeKernel((void*)lstm_persist, dim3(NWG), dim3(NTHR),
                               args, 0, stream);
}